// Round 18
// baseline (518.690 us; speedup 1.0000x reference)
//
#include <hip/hip_runtime.h>

typedef __attribute__((ext_vector_type(8))) short bf16x8;
typedef __attribute__((ext_vector_type(8))) unsigned short u16x8;
typedef __attribute__((ext_vector_type(4))) float f32x4;
typedef __attribute__((ext_vector_type(2))) unsigned uint2v;
typedef __attribute__((ext_vector_type(4))) unsigned uint4v;

#define DEVINL __device__ __forceinline__

constexpr int TB = 2;        // batch
constexpr int TT = 4096;     // seq len
constexpr int TD = 512;      // model dim
constexpr int TH = 8;        // heads
constexpr int THD = 64;      // head dim
constexpr int TM = TB * TT;  // 8192 flattened rows

// fp32 -> bf16 round-to-nearest-even
DEVINL unsigned short f2b(float f) {
  unsigned u = __builtin_bit_cast(unsigned, f);
  u += 0x7FFFu + ((u >> 16) & 1u);
  return (unsigned short)(u >> 16);
}

// pack 2 f32 -> 2 bf16 in one dword
DEVINL unsigned cvtpk(float lo, float hi) {
  unsigned r;
  asm("v_cvt_pk_bf16_f32 %0, %1, %2" : "=v"(r) : "v"(lo), "v"(hi));
  return r;
}

// barrier that only waits LDS ops (global stores may stay in flight)
DEVINL void lgkm_barrier() {
  asm volatile("s_waitcnt lgkmcnt(0)" ::: "memory");
  __builtin_amdgcn_s_barrier();
  __builtin_amdgcn_sched_barrier(0);
}

// ---------------------------------------------------------------------------
// Fused Q/K/V projection (r14 verbatim).
// ---------------------------------------------------------------------------
__global__ __launch_bounds__(256, 2)
void proj_qkv(const float* __restrict__ Xq, const float* __restrict__ Xk,
              const float* __restrict__ Xv, const float* __restrict__ Wq,
              const float* __restrict__ Wk, const float* __restrict__ Wv,
              unsigned short* __restrict__ qb, unsigned short* __restrict__ kb,
              unsigned short* __restrict__ vt)
{
  constexpr int K = TD, N = TD;
  __shared__ unsigned short As[128][72];
  __shared__ unsigned short Bs[128][72];

  const int z = blockIdx.z;
  const float* X = (z == 0) ? Xq : (z == 1) ? Xk : Xv;
  const float* W = (z == 0) ? Wq : (z == 1) ? Wk : Wv;
  unsigned short* Yb = (z == 0) ? qb : (z == 1) ? kb : vt;
  const bool TR = (z == 2);

  const int t    = threadIdx.x;
  const int lane = t & 63, w = t >> 6;
  const int fr = lane & 15, fq = lane >> 4;
  const int wr = (w >> 1) * 64, wc = (w & 1) * 64;
  const int bm = blockIdx.x * 128, bn = blockIdx.y * 128;
  const int srow = t >> 1;
  const int skh  = (t & 1) * 32;

  f32x4 acc[4][4];
  #pragma unroll
  for (int i = 0; i < 4; ++i)
    #pragma unroll
    for (int j = 0; j < 4; ++j)
      acc[i][j] = f32x4{0.f, 0.f, 0.f, 0.f};

  for (int k0 = 0; k0 < K; k0 += 64) {
    const float* srcA = X + (size_t)(bm + srow) * K + k0 + skh;
    const float* srcB = W + (size_t)(bn + srow) * K + k0 + skh;
    #pragma unroll
    for (int i = 0; i < 4; ++i) {
      float4 a0 = ((const float4*)srcA)[2 * i];
      float4 a1 = ((const float4*)srcA)[2 * i + 1];
      u16x8 oa = {f2b(a0.x), f2b(a0.y), f2b(a0.z), f2b(a0.w),
                  f2b(a1.x), f2b(a1.y), f2b(a1.z), f2b(a1.w)};
      *(u16x8*)&As[srow][skh + i * 8] = oa;
      float4 b0 = ((const float4*)srcB)[2 * i];
      float4 b1 = ((const float4*)srcB)[2 * i + 1];
      u16x8 ob = {f2b(b0.x), f2b(b0.y), f2b(b0.z), f2b(b0.w),
                  f2b(b1.x), f2b(b1.y), f2b(b1.z), f2b(b1.w)};
      *(u16x8*)&Bs[srow][skh + i * 8] = ob;
    }
    __syncthreads();
    #pragma unroll
    for (int kk = 0; kk < 2; ++kk) {
      bf16x8 af[4], bfv[4];
      #pragma unroll
      for (int i = 0; i < 4; ++i)
        af[i] = *(const bf16x8*)&As[wr + i * 16 + fr][kk * 32 + fq * 8];
      #pragma unroll
      for (int j = 0; j < 4; ++j)
        bfv[j] = *(const bf16x8*)&Bs[wc + j * 16 + fr][kk * 32 + fq * 8];
      if (TR) {
        #pragma unroll
        for (int i = 0; i < 4; ++i)
          #pragma unroll
          for (int j = 0; j < 4; ++j)
            acc[i][j] = __builtin_amdgcn_mfma_f32_16x16x32_bf16(bfv[i], af[j], acc[i][j], 0, 0, 0);
      } else {
        #pragma unroll
        for (int i = 0; i < 4; ++i)
          #pragma unroll
          for (int j = 0; j < 4; ++j)
            acc[i][j] = __builtin_amdgcn_mfma_f32_16x16x32_bf16(af[i], bfv[j], acc[i][j], 0, 0, 0);
      }
    }
    __syncthreads();
  }

  if (TR) {
    #pragma unroll
    for (int i = 0; i < 4; ++i)
      #pragma unroll
      for (int j = 0; j < 4; ++j)
        #pragma unroll
        for (int ii = 0; ii < 4; ++ii) {
          const int Nidx = bn + wc + i * 16 + fq * 4 + ii;
          const int Midx = bm + wr + j * 16 + fr;
          const int h = Nidx >> 6, dd = Nidx & (THD - 1);
          const int b = Midx >> 12, tt = Midx & (TT - 1);
          Yb[((size_t)(b * TH + h) * THD + dd) * TT + tt] = f2b(acc[i][j][ii]);
        }
  } else {
    #pragma unroll
    for (int i = 0; i < 4; ++i)
      #pragma unroll
      for (int j = 0; j < 4; ++j)
        #pragma unroll
        for (int ii = 0; ii < 4; ++ii) {
          const int gm = bm + wr + i * 16 + fq * 4 + ii;
          const int gn = bn + wc + j * 16 + fr;
          Yb[(size_t)gm * N + gn] = f2b(acc[i][j][ii]);
        }
  }
}

// ---------------------------------------------------------------------------
// Final GEMM: out = zf @ Wo^T + bo (fp32 out).  (r14 verbatim)
// ---------------------------------------------------------------------------
__global__ __launch_bounds__(256, 2)
void gemm_final(const float* __restrict__ X, const float* __restrict__ W,
                float* __restrict__ Yf, const float* __restrict__ bias)
{
  constexpr int K = TD, N = TD;
  __shared__ unsigned short As[128][72];
  __shared__ unsigned short Bs[128][72];

  const int t    = threadIdx.x;
  const int lane = t & 63, w = t >> 6;
  const int fr = lane & 15, fq = lane >> 4;
  const int wr = (w >> 1) * 64, wc = (w & 1) * 64;
  const int bm = blockIdx.x * 128, bn = blockIdx.y * 128;
  const int srow = t >> 1;
  const int skh  = (t & 1) * 32;

  f32x4 acc[4][4];
  #pragma unroll
  for (int i = 0; i < 4; ++i)
    #pragma unroll
    for (int j = 0; j < 4; ++j)
      acc[i][j] = f32x4{0.f, 0.f, 0.f, 0.f};

  for (int k0 = 0; k0 < K; k0 += 64) {
    const float* srcA = X + (size_t)(bm + srow) * K + k0 + skh;
    const float* srcB = W + (size_t)(bn + srow) * K + k0 + skh;
    #pragma unroll
    for (int i = 0; i < 4; ++i) {
      float4 a0 = ((const float4*)srcA)[2 * i];
      float4 a1 = ((const float4*)srcA)[2 * i + 1];
      u16x8 oa = {f2b(a0.x), f2b(a0.y), f2b(a0.z), f2b(a0.w),
                  f2b(a1.x), f2b(a1.y), f2b(a1.z), f2b(a1.w)};
      *(u16x8*)&As[srow][skh + i * 8] = oa;
      float4 b0 = ((const float4*)srcB)[2 * i];
      float4 b1 = ((const float4*)srcB)[2 * i + 1];
      u16x8 ob = {f2b(b0.x), f2b(b0.y), f2b(b0.z), f2b(b0.w),
                  f2b(b1.x), f2b(b1.y), f2b(b1.z), f2b(b1.w)};
      *(u16x8*)&Bs[srow][skh + i * 8] = ob;
    }
    __syncthreads();
    #pragma unroll
    for (int kk = 0; kk < 2; ++kk) {
      bf16x8 af[4], bfv[4];
      #pragma unroll
      for (int i = 0; i < 4; ++i)
        af[i] = *(const bf16x8*)&As[wr + i * 16 + fr][kk * 32 + fq * 8];
      #pragma unroll
      for (int j = 0; j < 4; ++j)
        bfv[j] = *(const bf16x8*)&Bs[wc + j * 16 + fr][kk * 32 + fq * 8];
      #pragma unroll
      for (int i = 0; i < 4; ++i)
        #pragma unroll
        for (int j = 0; j < 4; ++j)
          acc[i][j] = __builtin_amdgcn_mfma_f32_16x16x32_bf16(af[i], bfv[j], acc[i][j], 0, 0, 0);
    }
    __syncthreads();
  }

  #pragma unroll
  for (int i = 0; i < 4; ++i)
    #pragma unroll
    for (int j = 0; j < 4; ++j)
      #pragma unroll
      for (int ii = 0; ii < 4; ++ii) {
        const int gm = bm + wr + i * 16 + fq * 4 + ii;
        const int gn = bn + wc + j * 16 + fr;
        Yf[(size_t)gm * N + gn] = acc[i][j][ii] + bias[gn];
      }
}

// ---------------------------------------------------------------------------
// PASS 1a: kv-split partials. 2048 blocks; block d = (ds = d>>1, kh = d&1)
// handles kv half kh of (bh, q0). Writes UNNORMALIZED accz partial and lsum
// partial into scratch (the attn buffer — overwritten later by pass 2).
// Structure identical to r14 pass1 (distance-2 staged pipeline), 64 tiles.
// launch_bounds(256,6): 24 waves/CU (1.5x r14's residency), VGPR cap 85.
// ---------------------------------------------------------------------------
__global__ __launch_bounds__(256, 6)
void attn_pass1p(const unsigned short* __restrict__ Qb,
                 const unsigned short* __restrict__ Kb,
                 const unsigned short* __restrict__ VTg,
                 float* __restrict__ acczP, float* __restrict__ lsumP)
{
  __shared__ unsigned short Ks[2][32][72];     // 9.0 KB
  __shared__ unsigned short VTs[2][64][40];    // 10.0 KB

  const int t    = threadIdx.x;
  const int lane = t & 63, w = t >> 6;
  const int fr = lane & 15, fq = lane >> 4;

  const int d  = blockIdx.x;                   // 0..2047
  const int ds = d >> 1, kh = d & 1;
  const int bh = 2 * (ds & 7) + ((ds >> 3) & 1); // 2 bh per XCD
  const int q0 = (ds >> 4) * 64;
  const int b  = bh >> 3, h = bh & 7;
  const int kvBase = kh * (TT / 2);            // this block's kv half

  const size_t rowKV  = ((size_t)(b * TT)) * TD + h * THD;
  const size_t vtBase = (size_t)bh * THD * TT;

  const int trK = t >> 3, tcK = (t & 7) * 8;
  const int trV = t >> 2, tcV = (t & 3) * 8;

  auto loadK = [&](int kv0, u16x8& r) {
    r = *(const u16x8*)(Kb + rowKV + (size_t)(kvBase + kv0 + trK) * TD + tcK);
  };
  auto loadVT = [&](int kv0, u16x8& r) {
    r = *(const u16x8*)(VTg + vtBase + (size_t)trV * TT + kvBase + kv0 + tcV);
  };
  auto writeK  = [&](int buf, const u16x8& r) { *(u16x8*)&Ks[buf][trK][tcK]  = r; };
  auto writeVT = [&](int buf, const u16x8& r) { *(u16x8*)&VTs[buf][trV][tcV] = r; };

  const unsigned short* qsrc = Qb + ((size_t)(b * TT + q0 + w * 16 + fr)) * TD + h * THD;
  bf16x8 aq[2];
  aq[0] = *(const bf16x8*)(qsrc + fq * 8);
  aq[1] = *(const bf16x8*)(qsrc + 32 + fq * 8);

  constexpr int KVB = 32;
  constexpr int NT = TT / 2 / KVB;             // 64 tiles (half range)
  constexpr float K2 = 0.18033688011112042f;   // (1/8) * log2(e)

  u16x8 kA, vA, kB, vB;
  {
    u16x8 k0, v0;
    loadK(0, k0); loadVT(0, v0);
    writeK(0, k0); writeVT(0, v0);
    loadK(KVB, kB); loadVT(KVB, vB);
    lgkm_barrier();
  }

  float lsum = 0.f;
  f32x4 accz[4];
  #pragma unroll
  for (int n = 0; n < 4; ++n) accz[n] = f32x4{0.f, 0.f, 0.f, 0.f};

  for (int jp = 0; jp < NT / 2; ++jp) {
    #pragma unroll
    for (int half = 0; half < 2; ++half) {
      const int j = jp * 2 + half;
      const int cur = j & 1;
      if (j + 2 < NT) {
        if (half == 0) { loadK((j + 2) * KVB, kA); loadVT((j + 2) * KVB, vA); }
        else           { loadK((j + 2) * KVB, kB); loadVT((j + 2) * KVB, vB); }
      }
      f32x4 sv[2];
      __builtin_amdgcn_s_setprio(1);
      #pragma unroll
      for (int n = 0; n < 2; ++n) {
        f32x4 s = f32x4{0.f, 0.f, 0.f, 0.f};
        #pragma unroll
        for (int kk = 0; kk < 2; ++kk) {
          bf16x8 ak = *(const bf16x8*)&Ks[cur][n * 16 + fr][kk * 32 + fq * 8];
          s = __builtin_amdgcn_mfma_f32_16x16x32_bf16(ak, aq[kk], s, 0, 0, 0);
        }
        sv[n] = s;
      }
      __builtin_amdgcn_s_setprio(0);
      float p[2][4];
      #pragma unroll
      for (int n = 0; n < 2; ++n)
        #pragma unroll
        for (int i = 0; i < 4; ++i) {
          p[n][i] = __builtin_amdgcn_exp2f(sv[n][i] * K2);
          lsum += p[n][i];
        }
      uint4v pav = {cvtpk(p[0][0], p[0][1]), cvtpk(p[0][2], p[0][3]),
                    cvtpk(p[1][0], p[1][1]), cvtpk(p[1][2], p[1][3])};
      bf16x8 ap = __builtin_bit_cast(bf16x8, pav);
      __builtin_amdgcn_s_setprio(1);
      #pragma unroll
      for (int df = 0; df < 4; ++df) {
        uint2v lo = *(const uint2v*)&VTs[cur][df * 16 + fr][fq * 4];
        uint2v hi = *(const uint2v*)&VTs[cur][df * 16 + fr][16 + fq * 4];
        uint4v bvv = {lo[0], lo[1], hi[0], hi[1]};
        accz[df] = __builtin_amdgcn_mfma_f32_16x16x32_bf16(
            ap, __builtin_bit_cast(bf16x8, bvv), accz[df], 0, 0, 0);
      }
      __builtin_amdgcn_s_setprio(0);
      if (j + 1 < NT) {
        if (half == 0) { writeK(cur ^ 1, kB); writeVT(cur ^ 1, vB); }
        else           { writeK(cur ^ 1, kA); writeVT(cur ^ 1, vA); }
      }
      lgkm_barrier();
    }
  }

  // per-q partial lsum (q = w*16 + fr lane-local; kv slots across fq)
  lsum += __shfl_xor(lsum, 16, 64);
  lsum += __shfl_xor(lsum, 32, 64);
  if (fq == 0)
    lsumP[(size_t)d * 64 + w * 16 + fr] = lsum;

  // partial accz: acczP[d][q][dd], q = w*16+fq*4+i, dd = df*16+fr
  float* ab = acczP + (size_t)d * 4096 + (size_t)(w * 16 + fq * 4) * 64 + fr;
  #pragma unroll
  for (int df = 0; df < 4; ++df)
    #pragma unroll
    for (int i = 0; i < 4; ++i)
      ab[(size_t)i * 64 + df * 16] = accz[df][i];
}

// ---------------------------------------------------------------------------
// Reduce: combine kv-half partials -> normalized Z + l2i.
// Block ds (1024): Z rows (bh,q0..q0+63). Thread t: row q = t/4, cols
// (t%4)*16 .. +15.
// ---------------------------------------------------------------------------
__global__ __launch_bounds__(256, 8)
void reduce_z(const float* __restrict__ acczP, const float* __restrict__ lsumP,
              float* __restrict__ Z, float* __restrict__ l2iW)
{
  const int ds = blockIdx.x;
  const int bh = 2 * (ds & 7) + ((ds >> 3) & 1);
  const int q0 = (ds >> 4) * 64;
  const int b  = bh >> 3, h = bh & 7;

  const int t = threadIdx.x;
  const int q = t >> 2, c0 = (t & 3) * 16;

  const float l = lsumP[(size_t)(2 * ds) * 64 + q] +
                  lsumP[(size_t)(2 * ds + 1) * 64 + q];
  const float rinv = 1.0f / l;
  if ((t & 3) == 0)
    l2iW[(size_t)bh * TT + q0 + q] = -__log2f(l);

  const float* a0 = acczP + (size_t)(2 * ds) * 4096 + (size_t)q * 64 + c0;
  const float* a1 = acczP + (size_t)(2 * ds + 1) * 4096 + (size_t)q * 64 + c0;
  float* zdst = Z + (size_t)(b * TT + q0 + q) * TD + h * THD + c0;
  #pragma unroll
  for (int i = 0; i < 4; ++i) {
    f32x4 v0 = *(const f32x4*)(a0 + i * 4);
    f32x4 v1 = *(const f32x4*)(a1 + i * 4);
    f32x4 r = {(v0[0] + v1[0]) * rinv, (v0[1] + v1[1]) * rinv,
               (v0[2] + v1[2]) * rinv, (v0[3] + v1[3]) * rinv};
    *(f32x4*)(zdst + i * 4) = r;
  }
}

// ---------------------------------------------------------------------------
// PASS 2: r14 verbatim — phase-staggered streamer, per-wave double-buffered
// LDS staging, named sA/sB distance-2 sets, barrier-free.
// ---------------------------------------------------------------------------
__global__ __launch_bounds__(256, 4)
void attn_pass2(const unsigned short* __restrict__ Qb,
                const unsigned short* __restrict__ Kb,
                const float* __restrict__ l2iW,
                float* __restrict__ attnO)
{
  __shared__ unsigned short KsW[4][2][32][72];   // 36.9 KB per-wave dbuf

  const int t    = threadIdx.x;
  const int lane = t & 63, w = t >> 6;
  const int fr = lane & 15, fq = lane >> 4;

  const int d  = blockIdx.x;
  const int bh = 2 * (d & 7) + ((d >> 3) & 1);
  const int q0 = (d >> 4) * 64;
  const int b  = bh >> 3, h = bh & 7;

  const size_t rowKV = ((size_t)(b * TT)) * TD + h * THD;

  const unsigned short* qsrc = Qb + ((size_t)(b * TT + q0 + w * 16 + fr)) * TD + h * THD;
  bf16x8 aq[2];
  aq[0] = *(const bf16x8*)(qsrc + fq * 8);
  aq[1] = *(const bf16x8*)(qsrc + 32 + fq * 8);

  const float l2i = l2iW[(size_t)bh * TT + q0 + w * 16 + fr];

  constexpr int KVB = 32;
  constexpr int NT = TT / KVB;                  // 128
  constexpr float K2 = 0.18033688011112042f;

  const int phase = (37 * d + 32 * w) & (NT - 1);
  const int prow = lane >> 3, pcol = (lane & 7) * 8;

  u16x8 sA[4], sB[4];
  auto loadKW = [&](int kvt, u16x8* s) {
    #pragma unroll
    for (int i = 0; i < 4; ++i)
      s[i] = *(const u16x8*)(Kb + rowKV +
               (size_t)(kvt * KVB + i * 8 + prow) * TD + pcol);
  };
  auto writeKW = [&](int buf, const u16x8* s) {
    #pragma unroll
    for (int i = 0; i < 4; ++i)
      *(u16x8*)&KsW[w][buf][i * 8 + prow][pcol] = s[i];
  };
  auto PH = [&](int jj) { return (jj + phase) & (NT - 1); };

  float* arow = attnO + ((size_t)bh * TT + q0 + w * 16 + fr) * TT + fq * 4;

#define P2_COMPUTE(JJ, BUF)                                                    \
  {                                                                            \
    const int j = PH(JJ);                                                      \
    f32x4 sv[2];                                                               \
    __builtin_amdgcn_s_setprio(1);                                             \
    _Pragma("unroll")                                                          \
    for (int n = 0; n < 2; ++n) {                                              \
      f32x4 s = f32x4{0.f, 0.f, 0.f, 0.f};                                     \
      _Pragma("unroll")                                                        \
      for (int kk = 0; kk < 2; ++kk) {                                         \
        bf16x8 ak = *(const bf16x8*)&KsW[w][(BUF)][n * 16 + fr][kk * 32 + fq * 8]; \
        s = __builtin_amdgcn_mfma_f32_16x16x32_bf16(ak, aq[kk], s, 0, 0, 0);   \
      }                                                                        \
      sv[n] = s;                                                               \
    }                                                                          \
    __builtin_amdgcn_s_setprio(0);                                             \
    _Pragma("unroll")                                                          \
    for (int n = 0; n < 2; ++n) {                                              \
      f32x4 pv4 = {__builtin_amdgcn_exp2f(fmaf(sv[n][0], K2, l2i)),            \
                   __builtin_amdgcn_exp2f(fmaf(sv[n][1], K2, l2i)),            \
                   __builtin_amdgcn_exp2f(fmaf(sv[n][2], K2, l2i)),            \
                   __builtin_amdgcn_exp2f(fmaf(sv[n][3], K2, l2i))};           \
      *(f32x4*)(arow + j * KVB + n * 16) = pv4;                                \
    }                                                                          \
  }

  loadKW(PH(0), sA);
  writeKW(0, sA);
  loadKW(PH(1), sB);

  for (int jp = 0; jp < NT / 2; ++jp) {
    const int jj0 = 2 * jp;
    if (jj0 + 2 < NT) loadKW(PH(jj0 + 2), sA);
    P2_COMPUTE(jj0, 0)
    writeKW(1, sB);
    if (jj0 + 3 < NT) loadKW(PH(jj0 + 3), sB);
    P2_COMPUTE(jj0 + 1, 1)
    if (jj0 + 2 < NT) writeKW(0, sA);
  }
#undef P2_COMPUTE
}

// ---------------------------------------------------------------------------
extern "C" void kernel_launch(void* const* d_in, const int* in_sizes, int n_in,
                              void* d_out, int out_size, void* d_ws, size_t ws_size,
                              hipStream_t stream) {
  const float* queries = (const float*)d_in[0];
  const float* keys    = (const float*)d_in[1];
  const float* values  = (const float*)d_in[2];
  const float* Wq = (const float*)d_in[3];
  const float* Wk = (const float*)d_in[4];
  const float* Wv = (const float*)d_in[5];
  const float* Wo = (const float*)d_in[6];
  const float* bo = (const float*)d_in[7];

  float* out  = (float*)d_out;                       // [2,4096,512]
  float* attn = out + (size_t)TM * TD;               // [2,8,4096,4096]

  unsigned short* qb = (unsigned short*)d_ws;
  unsigned short* kb = qb + (size_t)TM * TD;
  unsigned short* vt = kb + (size_t)TM * TD;
  float*          zf = (float*)(vt + (size_t)TM * TD);
  float*          l2iW = zf + (size_t)TM * TD;       // [16][4096]

  // partials live in the attn buffer (overwritten later by pass 2)
  float* acczP = attn;                               // [2048][4096] = 33.5 MB
  float* lsumP = attn + (size_t)2048 * 4096;         // [2048][64]   = 0.5 MB

  proj_qkv<<<dim3(TM / 128, TD / 128, 3), 256, 0, stream>>>(
      queries, keys, values, Wq, Wk, Wv, qb, kb, vt);

  attn_pass1p<<<dim3(2048), 256, 0, stream>>>(qb, kb, vt, acczP, lsumP);

  reduce_z<<<dim3(1024), 256, 0, stream>>>(acczP, lsumP, zf, l2iW);

  attn_pass2<<<dim3(1024), 256, 0, stream>>>(qb, kb, l2iW, attn);

  gemm_final<<<dim3(TM / 128, TD / 128), 256, 0, stream>>>(zf, Wo, out, bo);
}

// Round 19
// 492.758 us; speedup vs baseline: 1.0526x; 1.0526x over previous
//
#include <hip/hip_runtime.h>

typedef __attribute__((ext_vector_type(8))) short bf16x8;
typedef __attribute__((ext_vector_type(8))) unsigned short u16x8;
typedef __attribute__((ext_vector_type(4))) float f32x4;
typedef __attribute__((ext_vector_type(2))) unsigned uint2v;
typedef __attribute__((ext_vector_type(4))) unsigned uint4v;

#define DEVINL __device__ __forceinline__

constexpr int TB = 2;        // batch
constexpr int TT = 4096;     // seq len
constexpr int TD = 512;      // model dim
constexpr int TH = 8;        // heads
constexpr int THD = 64;      // head dim
constexpr int TM = TB * TT;  // 8192 flattened rows

// fp32 -> bf16 round-to-nearest-even
DEVINL unsigned short f2b(float f) {
  unsigned u = __builtin_bit_cast(unsigned, f);
  u += 0x7FFFu + ((u >> 16) & 1u);
  return (unsigned short)(u >> 16);
}

// pack 2 f32 -> 2 bf16 in one dword
DEVINL unsigned cvtpk(float lo, float hi) {
  unsigned r;
  asm("v_cvt_pk_bf16_f32 %0, %1, %2" : "=v"(r) : "v"(lo), "v"(hi));
  return r;
}

// barrier that only waits LDS ops (global stores may stay in flight)
DEVINL void lgkm_barrier() {
  asm volatile("s_waitcnt lgkmcnt(0)" ::: "memory");
  __builtin_amdgcn_s_barrier();
  __builtin_amdgcn_sched_barrier(0);
}

// ---------------------------------------------------------------------------
// Fused Q/K/V projection.
// ---------------------------------------------------------------------------
__global__ __launch_bounds__(256, 2)
void proj_qkv(const float* __restrict__ Xq, const float* __restrict__ Xk,
              const float* __restrict__ Xv, const float* __restrict__ Wq,
              const float* __restrict__ Wk, const float* __restrict__ Wv,
              unsigned short* __restrict__ qb, unsigned short* __restrict__ kb,
              unsigned short* __restrict__ vt)
{
  constexpr int K = TD, N = TD;
  __shared__ unsigned short As[128][72];
  __shared__ unsigned short Bs[128][72];

  const int z = blockIdx.z;
  const float* X = (z == 0) ? Xq : (z == 1) ? Xk : Xv;
  const float* W = (z == 0) ? Wq : (z == 1) ? Wk : Wv;
  unsigned short* Yb = (z == 0) ? qb : (z == 1) ? kb : vt;
  const bool TR = (z == 2);

  const int t    = threadIdx.x;
  const int lane = t & 63, w = t >> 6;
  const int fr = lane & 15, fq = lane >> 4;
  const int wr = (w >> 1) * 64, wc = (w & 1) * 64;
  const int bm = blockIdx.x * 128, bn = blockIdx.y * 128;
  const int srow = t >> 1;
  const int skh  = (t & 1) * 32;

  f32x4 acc[4][4];
  #pragma unroll
  for (int i = 0; i < 4; ++i)
    #pragma unroll
    for (int j = 0; j < 4; ++j)
      acc[i][j] = f32x4{0.f, 0.f, 0.f, 0.f};

  for (int k0 = 0; k0 < K; k0 += 64) {
    const float* srcA = X + (size_t)(bm + srow) * K + k0 + skh;
    const float* srcB = W + (size_t)(bn + srow) * K + k0 + skh;
    #pragma unroll
    for (int i = 0; i < 4; ++i) {
      float4 a0 = ((const float4*)srcA)[2 * i];
      float4 a1 = ((const float4*)srcA)[2 * i + 1];
      u16x8 oa = {f2b(a0.x), f2b(a0.y), f2b(a0.z), f2b(a0.w),
                  f2b(a1.x), f2b(a1.y), f2b(a1.z), f2b(a1.w)};
      *(u16x8*)&As[srow][skh + i * 8] = oa;
      float4 b0 = ((const float4*)srcB)[2 * i];
      float4 b1 = ((const float4*)srcB)[2 * i + 1];
      u16x8 ob = {f2b(b0.x), f2b(b0.y), f2b(b0.z), f2b(b0.w),
                  f2b(b1.x), f2b(b1.y), f2b(b1.z), f2b(b1.w)};
      *(u16x8*)&Bs[srow][skh + i * 8] = ob;
    }
    __syncthreads();
    #pragma unroll
    for (int kk = 0; kk < 2; ++kk) {
      bf16x8 af[4], bfv[4];
      #pragma unroll
      for (int i = 0; i < 4; ++i)
        af[i] = *(const bf16x8*)&As[wr + i * 16 + fr][kk * 32 + fq * 8];
      #pragma unroll
      for (int j = 0; j < 4; ++j)
        bfv[j] = *(const bf16x8*)&Bs[wc + j * 16 + fr][kk * 32 + fq * 8];
      if (TR) {
        #pragma unroll
        for (int i = 0; i < 4; ++i)
          #pragma unroll
          for (int j = 0; j < 4; ++j)
            acc[i][j] = __builtin_amdgcn_mfma_f32_16x16x32_bf16(bfv[i], af[j], acc[i][j], 0, 0, 0);
      } else {
        #pragma unroll
        for (int i = 0; i < 4; ++i)
          #pragma unroll
          for (int j = 0; j < 4; ++j)
            acc[i][j] = __builtin_amdgcn_mfma_f32_16x16x32_bf16(af[i], bfv[j], acc[i][j], 0, 0, 0);
      }
    }
    __syncthreads();
  }

  if (TR) {
    #pragma unroll
    for (int i = 0; i < 4; ++i)
      #pragma unroll
      for (int j = 0; j < 4; ++j)
        #pragma unroll
        for (int ii = 0; ii < 4; ++ii) {
          const int Nidx = bn + wc + i * 16 + fq * 4 + ii;
          const int Midx = bm + wr + j * 16 + fr;
          const int h = Nidx >> 6, dd = Nidx & (THD - 1);
          const int b = Midx >> 12, tt = Midx & (TT - 1);
          Yb[((size_t)(b * TH + h) * THD + dd) * TT + tt] = f2b(acc[i][j][ii]);
        }
  } else {
    #pragma unroll
    for (int i = 0; i < 4; ++i)
      #pragma unroll
      for (int j = 0; j < 4; ++j)
        #pragma unroll
        for (int ii = 0; ii < 4; ++ii) {
          const int gm = bm + wr + i * 16 + fq * 4 + ii;
          const int gn = bn + wc + j * 16 + fr;
          Yb[(size_t)gm * N + gn] = f2b(acc[i][j][ii]);
        }
  }
}

// ---------------------------------------------------------------------------
// Final GEMM: out = zf @ Wo^T + bo (fp32 out).
// ---------------------------------------------------------------------------
__global__ __launch_bounds__(256, 2)
void gemm_final(const float* __restrict__ X, const float* __restrict__ W,
                float* __restrict__ Yf, const float* __restrict__ bias)
{
  constexpr int K = TD, N = TD;
  __shared__ unsigned short As[128][72];
  __shared__ unsigned short Bs[128][72];

  const int t    = threadIdx.x;
  const int lane = t & 63, w = t >> 6;
  const int fr = lane & 15, fq = lane >> 4;
  const int wr = (w >> 1) * 64, wc = (w & 1) * 64;
  const int bm = blockIdx.x * 128, bn = blockIdx.y * 128;
  const int srow = t >> 1;
  const int skh  = (t & 1) * 32;

  f32x4 acc[4][4];
  #pragma unroll
  for (int i = 0; i < 4; ++i)
    #pragma unroll
    for (int j = 0; j < 4; ++j)
      acc[i][j] = f32x4{0.f, 0.f, 0.f, 0.f};

  for (int k0 = 0; k0 < K; k0 += 64) {
    const float* srcA = X + (size_t)(bm + srow) * K + k0 + skh;
    const float* srcB = W + (size_t)(bn + srow) * K + k0 + skh;
    #pragma unroll
    for (int i = 0; i < 4; ++i) {
      float4 a0 = ((const float4*)srcA)[2 * i];
      float4 a1 = ((const float4*)srcA)[2 * i + 1];
      u16x8 oa = {f2b(a0.x), f2b(a0.y), f2b(a0.z), f2b(a0.w),
                  f2b(a1.x), f2b(a1.y), f2b(a1.z), f2b(a1.w)};
      *(u16x8*)&As[srow][skh + i * 8] = oa;
      float4 b0 = ((const float4*)srcB)[2 * i];
      float4 b1 = ((const float4*)srcB)[2 * i + 1];
      u16x8 ob = {f2b(b0.x), f2b(b0.y), f2b(b0.z), f2b(b0.w),
                  f2b(b1.x), f2b(b1.y), f2b(b1.z), f2b(b1.w)};
      *(u16x8*)&Bs[srow][skh + i * 8] = ob;
    }
    __syncthreads();
    #pragma unroll
    for (int kk = 0; kk < 2; ++kk) {
      bf16x8 af[4], bfv[4];
      #pragma unroll
      for (int i = 0; i < 4; ++i)
        af[i] = *(const bf16x8*)&As[wr + i * 16 + fr][kk * 32 + fq * 8];
      #pragma unroll
      for (int j = 0; j < 4; ++j)
        bfv[j] = *(const bf16x8*)&Bs[wc + j * 16 + fr][kk * 32 + fq * 8];
      #pragma unroll
      for (int i = 0; i < 4; ++i)
        #pragma unroll
        for (int j = 0; j < 4; ++j)
          acc[i][j] = __builtin_amdgcn_mfma_f32_16x16x32_bf16(af[i], bfv[j], acc[i][j], 0, 0, 0);
    }
    __syncthreads();
  }

  #pragma unroll
  for (int i = 0; i < 4; ++i)
    #pragma unroll
    for (int j = 0; j < 4; ++j)
      #pragma unroll
      for (int ii = 0; ii < 4; ++ii) {
        const int gm = bm + wr + i * 16 + fq * 4 + ii;
        const int gn = bn + wc + j * 16 + fr;
        Yf[(size_t)gm * N + gn] = acc[i][j][ii] + bias[gn];
      }
}

// ---------------------------------------------------------------------------
// PASS 1: lsum + unnormalized PV -> Z (normalized) + l2i to ws.
// Distance-2 staging pipeline: loads for tile j+2 issue at iter j, ds_write
// of tile j+1 uses regs loaded one full iteration earlier (vmcnt slack).
// ---------------------------------------------------------------------------
__global__ __launch_bounds__(256, 4)
void attn_pass1(const unsigned short* __restrict__ Qb,
                const unsigned short* __restrict__ Kb,
                const unsigned short* __restrict__ VTg,
                float* __restrict__ Z, float* __restrict__ l2iW)
{
  __shared__ unsigned short Ks[2][32][72];     // 9.0 KB
  __shared__ unsigned short VTs[2][64][40];    // 10.0 KB

  const int t    = threadIdx.x;
  const int lane = t & 63, w = t >> 6;
  const int fr = lane & 15, fq = lane >> 4;

  const int d  = blockIdx.x;                   // 0..1023
  const int bh = 2 * (d & 7) + ((d >> 3) & 1); // 2 bh per XCD
  const int q0 = (d >> 4) * 64;
  const int b  = bh >> 3, h = bh & 7;

  const size_t rowKV  = ((size_t)(b * TT)) * TD + h * THD;
  const size_t vtBase = (size_t)bh * THD * TT;

  const int trK = t >> 3, tcK = (t & 7) * 8;
  const int trV = t >> 2, tcV = (t & 3) * 8;

  auto loadK = [&](int kv0, u16x8& r) {
    r = *(const u16x8*)(Kb + rowKV + (size_t)(kv0 + trK) * TD + tcK);
  };
  auto loadVT = [&](int kv0, u16x8& r) {
    r = *(const u16x8*)(VTg + vtBase + (size_t)trV * TT + kv0 + tcV);
  };
  auto writeK  = [&](int buf, const u16x8& r) { *(u16x8*)&Ks[buf][trK][tcK]  = r; };
  auto writeVT = [&](int buf, const u16x8& r) { *(u16x8*)&VTs[buf][trV][tcV] = r; };

  const unsigned short* qsrc = Qb + ((size_t)(b * TT + q0 + w * 16 + fr)) * TD + h * THD;
  bf16x8 aq[2];
  aq[0] = *(const bf16x8*)(qsrc + fq * 8);
  aq[1] = *(const bf16x8*)(qsrc + 32 + fq * 8);

  constexpr int KVB = 32;
  constexpr int NT = TT / KVB;                 // 128
  constexpr float K2 = 0.18033688011112042f;   // (1/8) * log2(e)

  // staging register sets: sX loaded at iter j lands in buf at iter j+1
  u16x8 kA, vA, kB, vB;
  {
    u16x8 k0, v0;
    loadK(0, k0); loadVT(0, v0);
    writeK(0, k0); writeVT(0, v0);             // vmcnt(0) once in prologue
    loadK(KVB, kB); loadVT(KVB, vB);           // tile 1 -> set B
    lgkm_barrier();
  }

  float lsum = 0.f;
  f32x4 accz[4];
  #pragma unroll
  for (int n = 0; n < 4; ++n) accz[n] = f32x4{0.f, 0.f, 0.f, 0.f};

  for (int jp = 0; jp < NT / 2; ++jp) {
    #pragma unroll
    for (int half = 0; half < 2; ++half) {
      const int j = jp * 2 + half;
      const int cur = j & 1;
      // load tile j+2 into the set NOT pending-write (even->A, odd->B)
      if (j + 2 < NT) {
        if (half == 0) { loadK((j + 2) * KVB, kA); loadVT((j + 2) * KVB, vA); }
        else           { loadK((j + 2) * KVB, kB); loadVT((j + 2) * KVB, vB); }
      }
      // compute tile j from buf[cur]
      f32x4 sv[2];
      __builtin_amdgcn_s_setprio(1);
      #pragma unroll
      for (int n = 0; n < 2; ++n) {
        f32x4 s = f32x4{0.f, 0.f, 0.f, 0.f};
        #pragma unroll
        for (int kk = 0; kk < 2; ++kk) {
          bf16x8 ak = *(const bf16x8*)&Ks[cur][n * 16 + fr][kk * 32 + fq * 8];
          s = __builtin_amdgcn_mfma_f32_16x16x32_bf16(ak, aq[kk], s, 0, 0, 0);
        }
        sv[n] = s;
      }
      __builtin_amdgcn_s_setprio(0);
      float p[2][4];
      #pragma unroll
      for (int n = 0; n < 2; ++n)
        #pragma unroll
        for (int i = 0; i < 4; ++i) {
          p[n][i] = __builtin_amdgcn_exp2f(sv[n][i] * K2);
          lsum += p[n][i];
        }
      uint4v pav = {cvtpk(p[0][0], p[0][1]), cvtpk(p[0][2], p[0][3]),
                    cvtpk(p[1][0], p[1][1]), cvtpk(p[1][2], p[1][3])};
      bf16x8 ap = __builtin_bit_cast(bf16x8, pav);
      __builtin_amdgcn_s_setprio(1);
      #pragma unroll
      for (int df = 0; df < 4; ++df) {
        uint2v lo = *(const uint2v*)&VTs[cur][df * 16 + fr][fq * 4];
        uint2v hi = *(const uint2v*)&VTs[cur][df * 16 + fr][16 + fq * 4];
        uint4v bvv = {lo[0], lo[1], hi[0], hi[1]};
        accz[df] = __builtin_amdgcn_mfma_f32_16x16x32_bf16(
            ap, __builtin_bit_cast(bf16x8, bvv), accz[df], 0, 0, 0);
      }
      __builtin_amdgcn_s_setprio(0);
      // stage tile j+1 (regs loaded at iter j-1: even writes B, odd writes A)
      if (j + 1 < NT) {
        if (half == 0) { writeK(cur ^ 1, kB); writeVT(cur ^ 1, vB); }
        else           { writeK(cur ^ 1, kA); writeVT(cur ^ 1, vA); }
      }
      lgkm_barrier();
    }
  }

  // full row sums (q = w*16+fr lane-local; kv split across fq)
  lsum += __shfl_xor(lsum, 16, 64);
  lsum += __shfl_xor(lsum, 32, 64);

  // l2i to ws (one lane per q)
  if (fq == 0)
    l2iW[(size_t)bh * TT + q0 + w * 16 + fr] = -__log2f(lsum);

  // Z = accz / lsum; accz row i is q = w*16 + fq*4 + i
  float rls[4];
  #pragma unroll
  for (int i = 0; i < 4; ++i)
    rls[i] = 1.0f / __shfl(lsum, fq * 4 + i, 64);
  const size_t zbase = ((size_t)(b * TT + q0 + w * 16 + fq * 4)) * TD + h * THD + fr;
  #pragma unroll
  for (int df = 0; df < 4; ++df)
    #pragma unroll
    for (int i = 0; i < 4; ++i)
      Z[zbase + (size_t)i * TD + df * 16] = accz[df][i] * rls[i];
}

// ---------------------------------------------------------------------------
// PASS 2: phase-staggered store streamer, per-wave staging,
// barrier-free, distance-2 pipeline (named sets sA/sB, unrolled pair loop).
// ---------------------------------------------------------------------------
__global__ __launch_bounds__(256, 4)
void attn_pass2(const unsigned short* __restrict__ Qb,
                const unsigned short* __restrict__ Kb,
                const float* __restrict__ l2iW,
                float* __restrict__ attnO)
{
  __shared__ unsigned short KsW[4][2][32][72];   // 36.9 KB per-wave dbuf

  const int t    = threadIdx.x;
  const int lane = t & 63, w = t >> 6;
  const int fr = lane & 15, fq = lane >> 4;

  const int d  = blockIdx.x;
  const int bh = 2 * (d & 7) + ((d >> 3) & 1);
  const int q0 = (d >> 4) * 64;
  const int b  = bh >> 3, h = bh & 7;

  const size_t rowKV = ((size_t)(b * TT)) * TD + h * THD;

  const unsigned short* qsrc = Qb + ((size_t)(b * TT + q0 + w * 16 + fr)) * TD + h * THD;
  bf16x8 aq[2];
  aq[0] = *(const bf16x8*)(qsrc + fq * 8);
  aq[1] = *(const bf16x8*)(qsrc + 32 + fq * 8);

  const float l2i = l2iW[(size_t)bh * TT + q0 + w * 16 + fr];

  constexpr int KVB = 32;
  constexpr int NT = TT / KVB;                  // 128
  constexpr float K2 = 0.18033688011112042f;

  const int phase = (37 * d + 32 * w) & (NT - 1);
  const int prow = lane >> 3, pcol = (lane & 7) * 8;

  u16x8 sA[4], sB[4];
  auto loadKW = [&](int kvt, u16x8* s) {
    #pragma unroll
    for (int i = 0; i < 4; ++i)
      s[i] = *(const u16x8*)(Kb + rowKV +
               (size_t)(kvt * KVB + i * 8 + prow) * TD + pcol);
  };
  auto writeKW = [&](int buf, const u16x8* s) {
    #pragma unroll
    for (int i = 0; i < 4; ++i)
      *(u16x8*)&KsW[w][buf][i * 8 + prow][pcol] = s[i];
  };
  auto PH = [&](int jj) { return (jj + phase) & (NT - 1); };

  float* arow = attnO + ((size_t)bh * TT + q0 + w * 16 + fr) * TT + fq * 4;

#define P2_COMPUTE(JJ, BUF)                                                    \
  {                                                                            \
    const int j = PH(JJ);                                                      \
    f32x4 sv[2];                                                               \
    __builtin_amdgcn_s_setprio(1);                                             \
    _Pragma("unroll")                                                          \
    for (int n = 0; n < 2; ++n) {                                              \
      f32x4 s = f32x4{0.f, 0.f, 0.f, 0.f};                                     \
      _Pragma("unroll")                                                        \
      for (int kk = 0; kk < 2; ++kk) {                                         \
        bf16x8 ak = *(const bf16x8*)&KsW[w][(BUF)][n * 16 + fr][kk * 32 + fq * 8]; \
        s = __builtin_amdgcn_mfma_f32_16x16x32_bf16(ak, aq[kk], s, 0, 0, 0);   \
      }                                                                        \
      sv[n] = s;                                                               \
    }                                                                          \
    __builtin_amdgcn_s_setprio(0);                                             \
    _Pragma("unroll")                                                          \
    for (int n = 0; n < 2; ++n) {                                              \
      f32x4 pv4 = {__builtin_amdgcn_exp2f(fmaf(sv[n][0], K2, l2i)),            \
                   __builtin_amdgcn_exp2f(fmaf(sv[n][1], K2, l2i)),            \
                   __builtin_amdgcn_exp2f(fmaf(sv[n][2], K2, l2i)),            \
                   __builtin_amdgcn_exp2f(fmaf(sv[n][3], K2, l2i))};           \
      *(f32x4*)(arow + j * KVB + n * 16) = pv4;                                \
    }                                                                          \
  }

  // prologue: tile0 -> buf0; tile1 -> sB
  loadKW(PH(0), sA);
  writeKW(0, sA);              // compiler inserts the one prologue vmcnt
  loadKW(PH(1), sB);

  for (int jp = 0; jp < NT / 2; ++jp) {
    const int jj0 = 2 * jp;
    // even: read buf0 (tile jj0); load jj0+2 -> sA; write buf1 from sB (jj0+1)
    if (jj0 + 2 < NT) loadKW(PH(jj0 + 2), sA);
    P2_COMPUTE(jj0, 0)
    writeKW(1, sB);
    // odd: read buf1 (tile jj0+1); load jj0+3 -> sB; write buf0 from sA
    if (jj0 + 3 < NT) loadKW(PH(jj0 + 3), sB);
    P2_COMPUTE(jj0 + 1, 1)
    if (jj0 + 2 < NT) writeKW(0, sA);
  }
#undef P2_COMPUTE
}

// ---------------------------------------------------------------------------
extern "C" void kernel_launch(void* const* d_in, const int* in_sizes, int n_in,
                              void* d_out, int out_size, void* d_ws, size_t ws_size,
                              hipStream_t stream) {
  const float* queries = (const float*)d_in[0];
  const float* keys    = (const float*)d_in[1];
  const float* values  = (const float*)d_in[2];
  const float* Wq = (const float*)d_in[3];
  const float* Wk = (const float*)d_in[4];
  const float* Wv = (const float*)d_in[5];
  const float* Wo = (const float*)d_in[6];
  const float* bo = (const float*)d_in[7];

  float* out  = (float*)d_out;                       // [2,4096,512]
  float* attn = out + (size_t)TM * TD;               // [2,8,4096,4096]

  unsigned short* qb = (unsigned short*)d_ws;
  unsigned short* kb = qb + (size_t)TM * TD;
  unsigned short* vt = kb + (size_t)TM * TD;
  float*          zf = (float*)(vt + (size_t)TM * TD);
  float*          l2iW = zf + (size_t)TM * TD;       // [16][4096]

  proj_qkv<<<dim3(TM / 128, TD / 128, 3), 256, 0, stream>>>(
      queries, keys, values, Wq, Wk, Wv, qb, kb, vt);

  attn_pass1<<<dim3(1024), 256, 0, stream>>>(qb, kb, vt, zf, l2iW);

  attn_pass2<<<dim3(1024), 256, 0, stream>>>(qb, kb, l2iW, attn);

  gemm_final<<<dim3(TM / 128, TD / 128), 256, 0, stream>>>(zf, Wo, out, bo);
}